// Round 7
// baseline (92.788 us; speedup 1.0000x reference)
//
#include <hip/hip_runtime.h>
#include <hip/hip_fp16.h>
#include <cstdint>

// Problem constants
#define BB   4
#define IH   64
#define IW   64
#define HWN  4096
#define NVN  16
#define NSN  16

// dtypes (established R1-R3): all inputs f32, output f32.
//
// R6 post-mortem: stride-49 "bank fix" neutral -- b128 16-lane groups cover
// all 32 banks exactly 2x at stride 48 AND 49 (no conflicts existed). seprot
// pipe floors: LDS 3.8us, VALU 3.2us vs ~14us measured -> stall-bound at the
// 16-waves/CU occupancy cap (grid 1024 blocks = 4/CU).
// R7: explicit gather phase (all 9 lgn + 9 g1 loads in flight before compute),
// v_dot2_f32_f16 for all dot-reductions (shorter f16 chains, f32 accum),
// branchless valid, launch_bounds(256,4).

// ws layout (16B-aligned offsets):
//   lgnT f16 [b][hw][64ch]          : 4*4096*64*2  = 2 MiB
//   Ews  f16 [b][nv][n][j*4+k2]     : 4*16*16*16*2 = 32 KiB
//   Cws  f16 [nv][o][k2*4+l]        : 16*16*16*2   = 8 KiB
#define EWS_OFF  (BB*HWN*64*2)
#define CWS_OFF  (EWS_OFF + BB*NVN*NSN*16*2)

struct __align__(16) H2x4 { __half2 h[4]; };
struct __align__(8)  H2x2 { __half2 a, b; };

typedef _Float16 hvec2 __attribute__((ext_vector_type(2)));

static __device__ __forceinline__ float fdot2f(__half2 a, __half2 b, float c) {
    union { __half2 h; hvec2 v; } ua, ub;
    ua.h = a; ub.h = b;
    return __builtin_amdgcn_fdot2(ua.v, ub.v, c, false);
}

__global__ __launch_bounds__(256) void prep_kernel(
    const float* __restrict__ lgn, const float* __restrict__ theta,
    const float* __restrict__ coefx, const float* __restrict__ coefy,
    const float* __restrict__ coefr, char* __restrict__ ws)
{
    const int blk = blockIdx.x, t = threadIdx.x;
    if (blk < 512) {
        // transpose lgn [b][c][hw] f32 -> lgnT [b][hw][c] f16 (32-pixel tiles)
        __shared__ float tile[64][33];
        const int b      = blk >> 7;
        const int hwbase = (blk & 127) << 5;
        const float* src = lgn + (size_t)b * (64 * HWN) + hwbase;
        const int x4 = t & 7;
        const int c0 = t >> 3;
        #pragma unroll
        for (int i = 0; i < 2; ++i) {
            const int c = c0 + i * 32;
            const float4 v = *(const float4*)&src[c * HWN + x4 * 4];
            tile[c][x4 * 4 + 0] = v.x;
            tile[c][x4 * 4 + 1] = v.y;
            tile[c][x4 * 4 + 2] = v.z;
            tile[c][x4 * 4 + 3] = v.w;
        }
        __syncthreads();
        __half2* dst = (__half2*)ws + (size_t)b * (HWN * 32) + (size_t)hwbase * 32;
        const int cp = t & 31, hw0 = t >> 5;
        #pragma unroll
        for (int i = 0; i < 4; ++i) {
            const int hw = hw0 + i * 8;
            dst[hw * 32 + cp] =
                __floats2half2_rn(tile[2 * cp][hw], tile[2 * cp + 1][hw]);
        }
    } else if (blk < 544) {
        // E[b][nv][n][j*4+k2] = sum_k1 coefx[nv,j,k1,n] *
        //   (wz0*coefy[nv,k1,k2,m0c] + wz1*coefy[nv,k1,k2,m1c])
        const int p  = (blk - 512) * 256 + t;        // 8192 half2 pairs
        const int b  = p >> 11, nv = (p >> 7) & 15, n = (p >> 3) & 15, q = p & 7;
        const float th  = theta[b] * 0.31830988618379067154f;
        const float zf  = (th + 1.0f) * 8.0f - 0.5f;
        const float zfl = floorf(zf);
        const float fz  = zf - zfl;
        const int   m0  = (int)zfl;
        const float wz0 = (m0 >= 0 && m0 <= 15) ? (1.0f - fz) : 0.0f;
        const float wz1 = (m0 + 1 >= 0 && m0 + 1 <= 15) ? fz : 0.0f;
        const int   m0c = min(max(m0, 0), 15), m1c = min(max(m0 + 1, 0), 15);
        float ev[2];
        #pragma unroll
        for (int s = 0; s < 2; ++s) {
            const int idx = 2 * q + s, j = idx >> 2, k2 = idx & 3;
            float e = 0.0f;
            #pragma unroll
            for (int k1 = 0; k1 < 4; ++k1) {
                const float a  = coefx[nv * 256 + (j * 4 + k1) * 16 + n];
                const float bm = wz0 * coefy[nv * 256 + (k1 * 4 + k2) * 16 + m0c]
                               + wz1 * coefy[nv * 256 + (k1 * 4 + k2) * 16 + m1c];
                e += a * bm;
            }
            ev[s] = e;
        }
        ((__half2*)(ws + EWS_OFF))[p] = __floats2half2_rn(ev[0], ev[1]);
    } else {
        // C repack: Cws[nv][o][k2*4+l] = coefr[nv,k2,l,o]
        const int p = (blk - 544) * 256 + t;
        if (p < 2048) {
            const int nv = p >> 7, o = (p >> 3) & 15, q = p & 7;
            const float c0 = coefr[nv * 256 + (2 * q + 0) * 16 + o];
            const float c1 = coefr[nv * 256 + (2 * q + 1) * 16 + o];
            ((__half2*)(ws + CWS_OFF))[p] = __floats2half2_rn(c0, c1);
        }
    }
}

// LDS C/E layout: 16B units, unit(nv,o,u) = o*49 + nv*3 + u (u=0,1 data).
__global__ __launch_bounds__(256, 4) void seprot_kernel(
    const float* __restrict__ grid1,
    const float* __restrict__ grid2,
    const char*  __restrict__ ws,
    float* __restrict__ out)
{
    __shared__ H2x4 sC[16 * 49];        // 12.25 KiB
    __shared__ H2x4 sE[16 * 49];        // 12.25 KiB
    __shared__ float sOut[16][17][4];   // 4.25 KiB store-coalescing stage

    const int t   = threadIdx.x;
    const int blk = blockIdx.x;
    const int b      = blk >> 8;             // block-uniform
    const int hwbase = (blk & 255) << 4;     // 16 pixels per block
    const int pg = t >> 4;                   // pixel in block (0..15)
    const int nv = t & 15;                   // lane-group = 16 nv of one pixel
    const int hw = hwbase + pg;

    // ---- stage C + E[b] (coalesced copy, padding applied here) ----
    {
        const H2x4* Cw = (const H2x4*)(ws + CWS_OFF);
        const H2x4* Ew = (const H2x4*)(ws + EWS_OFF) + b * 512;
        #pragma unroll
        for (int k = 0; k < 2; ++k) {
            const int i   = t + k * 256;
            const int wnv = i >> 5, wo = (i >> 1) & 15, wu = i & 1;
            const int du  = wo * 49 + wnv * 3 + wu;
            sC[du] = Cw[i];
            sE[du] = Ew[i];
        }
    }
    __syncthreads();

    // ---- per-pixel warp geometry (branchless; clamped center) ----
    const float2 g2  = ((const float2*)grid2)[b * HWN + hw];
    const float  sxf = rintf((g2.x + 1.0f) * (0.5f * IW) - 0.5f);
    const float  syf = rintf((g2.y + 1.0f) * (0.5f * IH) - 0.5f);
    const bool valid = (sxf >= 0.0f) && (sxf <= (float)(IW - 1)) &&
                       (syf >= 0.0f) && (syf <= (float)(IH - 1));
    const int sx = (int)fminf(fmaxf(sxf, 0.0f), 63.0f);
    const int sy = (int)fminf(fmaxf(syf, 0.0f), 63.0f);

    // ---- phase A: issue ALL tap loads before any dependent compute ----
    H2x2   lgu[9];
    float2 g1t[9];
    bool   inb[9];
    {
        const H2x2*   lgb = (const H2x2*)ws + (b * HWN) * 16 + nv;
        const float2* g1b = (const float2*)grid1 + b * HWN;
        #pragma unroll
        for (int tap = 0; tap < 9; ++tap) {
            const int di = tap / 3 - 1, dj = tap % 3 - 1;
            const int ty = sy + di, tx = sx + dj;
            inb[tap] = ((unsigned)ty < (unsigned)IH) && ((unsigned)tx < (unsigned)IW);
            const int pix = min(max(ty, 0), IH - 1) * IW + min(max(tx, 0), IW - 1);
            lgu[tap] = lgb[pix * 16];      // 16 nv-lanes -> one 128B segment
            g1t[tap] = g1b[pix];           // broadcast within 16-lane group
        }
    }

    // ---- phase B: per-tap separable trilinear compute ----
    float acc[4] = {0.0f, 0.0f, 0.0f, 0.0f};
    const __half2 zero2 = __floats2half2_rn(0.0f, 0.0f);

    #pragma unroll
    for (int tap = 0; tap < 9; ++tap) {
        const __half2 lg01 = inb[tap] ? lgu[tap].a : zero2;
        const __half2 lg23 = inb[tap] ? lgu[tap].b : zero2;
        const float dxc = g2.x - g1t[tap].x;
        const float dyc = g2.y - g1t[tap].y;

        // x -> coefr o axis
        const float xf  = (dxc + 1.0f) * (0.5f * NSN) - 0.5f;
        const float xfl = floorf(xf);
        const float fx  = xf - xfl;
        const int   o0  = (int)xfl;
        const float wx0 = (o0 >= 0 && o0 <= NSN - 1) ? (1.0f - fx) : 0.0f;
        const float wx1 = (o0 + 1 >= 0 && o0 + 1 <= NSN - 1) ? fx : 0.0f;
        const int   o0c = min(max(o0, 0), NSN - 1);
        const int   o1c = min(max(o0 + 1, 0), NSN - 1);

        // y -> coefx n axis
        const float yf  = (dyc + 1.0f) * (0.5f * NSN) - 0.5f;
        const float yfl = floorf(yf);
        const float fy  = yf - yfl;
        const int   n0  = (int)yfl;
        const float wy0 = (n0 >= 0 && n0 <= NSN - 1) ? (1.0f - fy) : 0.0f;
        const float wy1 = (n0 + 1 >= 0 && n0 + 1 <= NSN - 1) ? fy : 0.0f;
        const int   n0c = min(max(n0, 0), NSN - 1);
        const int   n1c = min(max(n0 + 1, 0), NSN - 1);

        const __half2 wx0h = __floats2half2_rn(wx0, wx0);
        const __half2 wx1h = __floats2half2_rn(wx1, wx1);
        const __half2 wy0h = __floats2half2_rn(wy0, wy0);
        const __half2 wy1h = __floats2half2_rn(wy1, wy1);

        // blended C rows (packed f16): bl[q] over [k2*2 + lpair]
        const H2x4 c0a = sC[o0c * 49 + nv * 3 + 0];
        const H2x4 c0b = sC[o0c * 49 + nv * 3 + 1];
        const H2x4 c1a = sC[o1c * 49 + nv * 3 + 0];
        const H2x4 c1b = sC[o1c * 49 + nv * 3 + 1];
        __half2 bl[8];
        #pragma unroll
        for (int k = 0; k < 4; ++k) {
            bl[k]     = __hfma2(c0a.h[k], wx0h, __hmul2(c1a.h[k], wx1h));
            bl[4 + k] = __hfma2(c0b.h[k], wx0h, __hmul2(c1b.h[k], wx1h));
        }
        // v_k2 = C'(x) . lg   (v_dot2_f32_f16, f32 accumulate)
        float vf[4];
        #pragma unroll
        for (int k2 = 0; k2 < 4; ++k2)
            vf[k2] = fdot2f(bl[2 * k2 + 1], lg23, fdot2f(bl[2 * k2], lg01, 0.0f));
        const __half2 v01 = __floats2half2_rn(vf[0], vf[1]);
        const __half2 v23 = __floats2half2_rn(vf[2], vf[3]);

        // blended E rows, then acc_j += E'(y) . v  (f32 accumulate)
        const H2x4 e0a = sE[n0c * 49 + nv * 3 + 0];
        const H2x4 e0b = sE[n0c * 49 + nv * 3 + 1];
        const H2x4 e1a = sE[n1c * 49 + nv * 3 + 0];
        const H2x4 e1b = sE[n1c * 49 + nv * 3 + 1];
        __half2 eb[8];
        #pragma unroll
        for (int k = 0; k < 4; ++k) {
            eb[k]     = __hfma2(e0a.h[k], wy0h, __hmul2(e1a.h[k], wy1h));
            eb[4 + k] = __hfma2(e0b.h[k], wy0h, __hmul2(e1b.h[k], wy1h));
        }
        #pragma unroll
        for (int j = 0; j < 4; ++j)
            acc[j] = fdot2f(eb[2 * j + 1], v23, fdot2f(eb[2 * j], v01, acc[j]));
    }

    // invalid center -> exact zero output
    #pragma unroll
    for (int j = 0; j < 4; ++j) acc[j] = valid ? acc[j] : 0.0f;

    // ---- store-coalescing LDS round-trip: swap nv<->pg lane roles ----
    *(float4*)&sOut[pg][nv][0] = make_float4(acc[0], acc[1], acc[2], acc[3]);
    __syncthreads();
    {
        const int nv2 = t >> 4, pg2 = t & 15;
        #pragma unroll
        for (int j = 0; j < 4; ++j)
            out[(b * 64 + nv2 * 4 + j) * HWN + hwbase + pg2] = sOut[pg2][nv2][j];
    }
}

extern "C" void kernel_launch(void* const* d_in, const int* in_sizes, int n_in,
                              void* d_out, int out_size, void* d_ws, size_t ws_size,
                              hipStream_t stream) {
    const float* grid1 = (const float*)d_in[0];
    const float* grid2 = (const float*)d_in[1];
    const float* theta = (const float*)d_in[2];
    const float* lgn   = (const float*)d_in[3];
    const float* coefx = (const float*)d_in[4];
    const float* coefy = (const float*)d_in[5];
    const float* coefr = (const float*)d_in[6];
    float*       outp  = (float*)d_out;
    char*        ws    = (char*)d_ws;

    hipLaunchKernelGGL(prep_kernel, dim3(552), dim3(256), 0, stream,
                       lgn, theta, coefx, coefy, coefr, ws);

    hipLaunchKernelGGL(seprot_kernel, dim3(BB * 256), dim3(256), 0, stream,
                       grid1, grid2, ws, outp);
}

// Round 8
// 83.578 us; speedup vs baseline: 1.1102x; 1.1102x over previous
//
#include <hip/hip_runtime.h>
#include <hip/hip_fp16.h>
#include <cstdint>

// Problem constants
#define BB   4
#define IH   64
#define IW   64
#define HWN  4096
#define NVN  16
#define NSN  16

// dtypes (established R1-R3): all inputs f32, output f32.
//
// R7 post-mortem: phase-A register buffer + launch_bounds(256,4) regressed
// 10us -> VGPR spills. Reverted to R6 inner loop.
// R8: occupancy attack. LDS-pipe floor of R6 = 72 ds_read_b128/thread ~ 5.8us
// at 16 waves/CU; stall was the rest. Split taps across 2 threads
// (lane layout pg|th|nv, uniform 5-tap loops w/ zero dummy, shfl_xor(16)
// reduction), 8 pixels/block, 2048 blocks; sOut aliased over dead sC ->
// 24.5 KB LDS -> 6 blocks/CU = 24 waves/CU (was 16).

// ws layout (16B-aligned offsets):
//   lgnT f16 [b][hw][64ch]          : 4*4096*64*2  = 2 MiB
//   Ews  f16 [b][nv][n][j*4+k2]     : 4*16*16*16*2 = 32 KiB
//   Cws  f16 [nv][o][k2*4+l]        : 16*16*16*2   = 8 KiB
#define EWS_OFF  (BB*HWN*64*2)
#define CWS_OFF  (EWS_OFF + BB*NVN*NSN*16*2)

struct __align__(16) H2x4 { __half2 h[4]; };
struct __align__(8)  H2x2 { __half2 a, b; };

__global__ __launch_bounds__(256) void prep_kernel(
    const float* __restrict__ lgn, const float* __restrict__ theta,
    const float* __restrict__ coefx, const float* __restrict__ coefy,
    const float* __restrict__ coefr, char* __restrict__ ws)
{
    const int blk = blockIdx.x, t = threadIdx.x;
    if (blk < 512) {
        // transpose lgn [b][c][hw] f32 -> lgnT [b][hw][c] f16 (32-pixel tiles)
        __shared__ float tile[64][33];
        const int b      = blk >> 7;
        const int hwbase = (blk & 127) << 5;
        const float* src = lgn + (size_t)b * (64 * HWN) + hwbase;
        const int x4 = t & 7;
        const int c0 = t >> 3;
        #pragma unroll
        for (int i = 0; i < 2; ++i) {
            const int c = c0 + i * 32;
            const float4 v = *(const float4*)&src[c * HWN + x4 * 4];
            tile[c][x4 * 4 + 0] = v.x;
            tile[c][x4 * 4 + 1] = v.y;
            tile[c][x4 * 4 + 2] = v.z;
            tile[c][x4 * 4 + 3] = v.w;
        }
        __syncthreads();
        __half2* dst = (__half2*)ws + (size_t)b * (HWN * 32) + (size_t)hwbase * 32;
        const int cp = t & 31, hw0 = t >> 5;
        #pragma unroll
        for (int i = 0; i < 4; ++i) {
            const int hw = hw0 + i * 8;
            dst[hw * 32 + cp] =
                __floats2half2_rn(tile[2 * cp][hw], tile[2 * cp + 1][hw]);
        }
    } else if (blk < 544) {
        // E[b][nv][n][j*4+k2] = sum_k1 coefx[nv,j,k1,n] *
        //   (wz0*coefy[nv,k1,k2,m0c] + wz1*coefy[nv,k1,k2,m1c])
        const int p  = (blk - 512) * 256 + t;        // 8192 half2 pairs
        const int b  = p >> 11, nv = (p >> 7) & 15, n = (p >> 3) & 15, q = p & 7;
        const float th  = theta[b] * 0.31830988618379067154f;
        const float zf  = (th + 1.0f) * 8.0f - 0.5f;
        const float zfl = floorf(zf);
        const float fz  = zf - zfl;
        const int   m0  = (int)zfl;
        const float wz0 = (m0 >= 0 && m0 <= 15) ? (1.0f - fz) : 0.0f;
        const float wz1 = (m0 + 1 >= 0 && m0 + 1 <= 15) ? fz : 0.0f;
        const int   m0c = min(max(m0, 0), 15), m1c = min(max(m0 + 1, 0), 15);
        float ev[2];
        #pragma unroll
        for (int s = 0; s < 2; ++s) {
            const int idx = 2 * q + s, j = idx >> 2, k2 = idx & 3;
            float e = 0.0f;
            #pragma unroll
            for (int k1 = 0; k1 < 4; ++k1) {
                const float a  = coefx[nv * 256 + (j * 4 + k1) * 16 + n];
                const float bm = wz0 * coefy[nv * 256 + (k1 * 4 + k2) * 16 + m0c]
                               + wz1 * coefy[nv * 256 + (k1 * 4 + k2) * 16 + m1c];
                e += a * bm;
            }
            ev[s] = e;
        }
        ((__half2*)(ws + EWS_OFF))[p] = __floats2half2_rn(ev[0], ev[1]);
    } else {
        // C repack: Cws[nv][o][k2*4+l] = coefr[nv,k2,l,o]
        const int p = (blk - 544) * 256 + t;
        if (p < 2048) {
            const int nv = p >> 7, o = (p >> 3) & 15, q = p & 7;
            const float c0 = coefr[nv * 256 + (2 * q + 0) * 16 + o];
            const float c1 = coefr[nv * 256 + (2 * q + 1) * 16 + o];
            ((__half2*)(ws + CWS_OFF))[p] = __floats2half2_rn(c0, c1);
        }
    }
}

// LDS C/E layout: 16B units, unit(nv,o,u) = o*49 + nv*3 + u (u=0,1 data).
// sOut aliases sC (dead after tap loop) -> total LDS 24.5 KB -> 6 blocks/CU.
__global__ __launch_bounds__(256) void seprot_kernel(
    const float* __restrict__ grid1,
    const float* __restrict__ grid2,
    const char*  __restrict__ ws,
    float* __restrict__ out)
{
    __shared__ __align__(16) char smem[2 * 16 * 49 * 16];   // 25088 B
    H2x4* sC = (H2x4*)smem;                 // 16*49 units
    H2x4* sE = (H2x4*)(smem + 16 * 49 * 16);
    float (*sOut)[17][4] = (float (*)[17][4])smem;  // alias over sC

    const int t   = threadIdx.x;
    const int blk = blockIdx.x;
    const int b      = blk >> 9;             // block-uniform (512 blocks / b)
    const int hwbase = (blk & 511) << 3;     // 8 pixels per block
    const int nv = t & 15;                   // lane-group = 16 nv of one pixel
    const int th = (t >> 4) & 1;             // tap-half
    const int pg = t >> 5;                   // pixel in block (0..7)
    const int hw = hwbase + pg;

    // ---- stage C + E[b] (coalesced copy, padding applied here) ----
    {
        const H2x4* Cw = (const H2x4*)(ws + CWS_OFF);
        const H2x4* Ew = (const H2x4*)(ws + EWS_OFF) + b * 512;
        #pragma unroll
        for (int k = 0; k < 2; ++k) {
            const int i   = t + k * 256;
            const int wnv = i >> 5, wo = (i >> 1) & 15, wu = i & 1;
            const int du  = wo * 49 + wnv * 3 + wu;
            sC[du] = Cw[i];
            sE[du] = Ew[i];
        }
    }
    __syncthreads();

    // ---- per-pixel warp geometry ----
    const float2 g2  = ((const float2*)grid2)[b * HWN + hw];
    const float  sxf = rintf((g2.x + 1.0f) * (0.5f * IW) - 0.5f);
    const float  syf = rintf((g2.y + 1.0f) * (0.5f * IH) - 0.5f);
    const bool valid = (sxf >= 0.0f) && (sxf <= (float)(IW - 1)) &&
                       (syf >= 0.0f) && (syf <= (float)(IH - 1));

    float acc[4] = {0.0f, 0.0f, 0.0f, 0.0f};

    if (valid) {
        const int sx = (int)sxf, sy = (int)syf;
        const __half2 zero2 = __floats2half2_rn(0.0f, 0.0f);
        const H2x2*   lgb = (const H2x2*)ws + (b * HWN) * 16 + nv;
        const float2* g1b = (const float2*)grid1 + b * HWN;

        // taps th*5 .. th*5+4; tap 9 is a zero-weight dummy (uniform trip count)
        #pragma unroll
        for (int i = 0; i < 5; ++i) {
            const int tap = th * 5 + i;
            const int tp  = min(tap, 8);
            const int di = tp / 3 - 1, dj = tp % 3 - 1;
            const int ty = sy + di, tx = sx + dj;
            const bool inb = (tap < 9) &&
                             ((unsigned)ty < (unsigned)IH) && ((unsigned)tx < (unsigned)IW);
            const int pix = min(max(ty, 0), IH - 1) * IW + min(max(tx, 0), IW - 1);

            // lgn 4-vec f16: 16 nv-lanes -> one 128B segment
            H2x2 lgu = lgb[pix * 16];
            const __half2 lg01 = inb ? lgu.a : zero2;
            const __half2 lg23 = inb ? lgu.b : zero2;

            // d = g2(center) - g1(tap); g1 broadcasts within the 16-lane group
            const float2 g1 = g1b[pix];
            const float dxc = g2.x - g1.x;
            const float dyc = g2.y - g1.y;

            // x -> coefr o axis
            const float xf  = (dxc + 1.0f) * (0.5f * NSN) - 0.5f;
            const float xfl = floorf(xf);
            const float fx  = xf - xfl;
            const int   o0  = (int)xfl;
            const float wx0 = (o0 >= 0 && o0 <= NSN - 1) ? (1.0f - fx) : 0.0f;
            const float wx1 = (o0 + 1 >= 0 && o0 + 1 <= NSN - 1) ? fx : 0.0f;
            const int   o0c = min(max(o0, 0), NSN - 1);
            const int   o1c = min(max(o0 + 1, 0), NSN - 1);

            // y -> coefx n axis
            const float yf  = (dyc + 1.0f) * (0.5f * NSN) - 0.5f;
            const float yfl = floorf(yf);
            const float fy  = yf - yfl;
            const int   n0  = (int)yfl;
            const float wy0 = (n0 >= 0 && n0 <= NSN - 1) ? (1.0f - fy) : 0.0f;
            const float wy1 = (n0 + 1 >= 0 && n0 + 1 <= NSN - 1) ? fy : 0.0f;
            const int   n0c = min(max(n0, 0), NSN - 1);
            const int   n1c = min(max(n0 + 1, 0), NSN - 1);

            const __half2 wx0h = __floats2half2_rn(wx0, wx0);
            const __half2 wx1h = __floats2half2_rn(wx1, wx1);
            const __half2 wy0h = __floats2half2_rn(wy0, wy0);
            const __half2 wy1h = __floats2half2_rn(wy1, wy1);

            // blended C rows (packed f16): bl[q] over [k2*2 + lpair]
            const H2x4 c0a = sC[o0c * 49 + nv * 3 + 0];
            const H2x4 c0b = sC[o0c * 49 + nv * 3 + 1];
            const H2x4 c1a = sC[o1c * 49 + nv * 3 + 0];
            const H2x4 c1b = sC[o1c * 49 + nv * 3 + 1];
            __half2 bl[8];
            #pragma unroll
            for (int k = 0; k < 4; ++k) {
                bl[k]     = __hfma2(c0a.h[k], wx0h, __hmul2(c1a.h[k], wx1h));
                bl[4 + k] = __hfma2(c0b.h[k], wx0h, __hmul2(c1b.h[k], wx1h));
            }
            // v_k2 = C'(x) . lg   (reduce each half2 pair in f32)
            float vf[4];
            #pragma unroll
            for (int k2 = 0; k2 < 4; ++k2) {
                const __half2 sv = __hfma2(bl[2 * k2 + 1], lg23,
                                           __hmul2(bl[2 * k2], lg01));
                vf[k2] = __low2float(sv) + __high2float(sv);
            }
            const __half2 v01 = __floats2half2_rn(vf[0], vf[1]);
            const __half2 v23 = __floats2half2_rn(vf[2], vf[3]);

            // blended E rows, then acc_j += E'(y) . v  (f32 accumulate)
            const H2x4 e0a = sE[n0c * 49 + nv * 3 + 0];
            const H2x4 e0b = sE[n0c * 49 + nv * 3 + 1];
            const H2x4 e1a = sE[n1c * 49 + nv * 3 + 0];
            const H2x4 e1b = sE[n1c * 49 + nv * 3 + 1];
            __half2 eb[8];
            #pragma unroll
            for (int k = 0; k < 4; ++k) {
                eb[k]     = __hfma2(e0a.h[k], wy0h, __hmul2(e1a.h[k], wy1h));
                eb[4 + k] = __hfma2(e0b.h[k], wy0h, __hmul2(e1b.h[k], wy1h));
            }
            #pragma unroll
            for (int j = 0; j < 4; ++j) {
                const __half2 sa = __hfma2(eb[2 * j + 1], v23,
                                           __hmul2(eb[2 * j], v01));
                acc[j] += __low2float(sa) + __high2float(sa);
            }
        }
    }

    // ---- reduce tap-halves (lanes l <-> l^16), all lanes active ----
    #pragma unroll
    for (int j = 0; j < 4; ++j)
        acc[j] += __shfl_xor(acc[j], 16, 64);

    // ---- store via LDS (aliases sC; sC dead) ----
    __syncthreads();
    if (th == 0)
        *(float4*)&sOut[pg][nv][0] = make_float4(acc[0], acc[1], acc[2], acc[3]);
    __syncthreads();
    {
        // 512 output floats/block; thread t writes 2 consecutive pixels
        const int ch = t >> 2;               // 0..63 = nv2*4 + j
        const int p0 = (t & 3) * 2;          // pixel pair 0,2,4,6
        const int nv2 = ch >> 2, j = ch & 3;
        float2 v2 = make_float2(sOut[p0][nv2][j], sOut[p0 + 1][nv2][j]);
        *(float2*)&out[(b * 64 + ch) * HWN + hwbase + p0] = v2;
    }
}

extern "C" void kernel_launch(void* const* d_in, const int* in_sizes, int n_in,
                              void* d_out, int out_size, void* d_ws, size_t ws_size,
                              hipStream_t stream) {
    const float* grid1 = (const float*)d_in[0];
    const float* grid2 = (const float*)d_in[1];
    const float* theta = (const float*)d_in[2];
    const float* lgn   = (const float*)d_in[3];
    const float* coefx = (const float*)d_in[4];
    const float* coefy = (const float*)d_in[5];
    const float* coefr = (const float*)d_in[6];
    float*       outp  = (float*)d_out;
    char*        ws    = (char*)d_ws;

    hipLaunchKernelGGL(prep_kernel, dim3(552), dim3(256), 0, stream,
                       lgn, theta, coefx, coefy, coefr, ws);

    // main: 2048 blocks, 8 pixels x 16 nv x 2 tap-halves per block
    hipLaunchKernelGGL(seprot_kernel, dim3(BB * 512), dim3(256), 0, stream,
                       grid1, grid2, ws, outp);
}

// Round 9
// 83.032 us; speedup vs baseline: 1.1175x; 1.0066x over previous
//
#include <hip/hip_runtime.h>
#include <hip/hip_fp16.h>
#include <cstdint>

// Problem constants
#define BB   4
#define IH   64
#define IW   64
#define HWN  4096
#define NVN  16
#define NSN  16

// dtypes (established R1-R3): all inputs f32, output f32.
//
// R9 = revert to R6 (measured best, 82.19us). Evidence ledger:
//   dur ~= 63us harness d_ws re-poison fills (268MB @ ~80% HBM peak, fixed)
//        + ~19us controllable (prep ~4 + seprot ~14 + launch overhead).
//   R6 bank-padding: neutral (b128 16-lane groups cover all 32 banks 2x at
//     stride 48 and 49 -- no conflicts ever existed).
//   R7 manual gather hoist + launch_bounds(256,4): -10us regression (spills).
//   R8 tap-split (24 waves/CU): neutral -- falsifies occupancy-stall theory.
//   => seprot is near its aggregate-LDS floor (~302MB coef reads ~ 4.4us at
//   69TB/s) + VALU ~3us + latency residue; no written theory predicts >5us.

// ws layout (16B-aligned offsets):
//   lgnT f16 [b][hw][64ch]          : 4*4096*64*2  = 2 MiB
//   Ews  f16 [b][nv][n][j*4+k2]     : 4*16*16*16*2 = 32 KiB
//   Cws  f16 [nv][o][k2*4+l]        : 16*16*16*2   = 8 KiB
#define EWS_OFF  (BB*HWN*64*2)
#define CWS_OFF  (EWS_OFF + BB*NVN*NSN*16*2)

struct __align__(16) H2x4 { __half2 h[4]; };
struct __align__(8)  H2x2 { __half2 a, b; };

__global__ __launch_bounds__(256) void prep_kernel(
    const float* __restrict__ lgn, const float* __restrict__ theta,
    const float* __restrict__ coefx, const float* __restrict__ coefy,
    const float* __restrict__ coefr, char* __restrict__ ws)
{
    const int blk = blockIdx.x, t = threadIdx.x;
    if (blk < 512) {
        // transpose lgn [b][c][hw] f32 -> lgnT [b][hw][c] f16 (32-pixel tiles)
        __shared__ float tile[64][33];
        const int b      = blk >> 7;
        const int hwbase = (blk & 127) << 5;
        const float* src = lgn + (size_t)b * (64 * HWN) + hwbase;
        const int x4 = t & 7;
        const int c0 = t >> 3;
        #pragma unroll
        for (int i = 0; i < 2; ++i) {
            const int c = c0 + i * 32;
            const float4 v = *(const float4*)&src[c * HWN + x4 * 4];
            tile[c][x4 * 4 + 0] = v.x;
            tile[c][x4 * 4 + 1] = v.y;
            tile[c][x4 * 4 + 2] = v.z;
            tile[c][x4 * 4 + 3] = v.w;
        }
        __syncthreads();
        __half2* dst = (__half2*)ws + (size_t)b * (HWN * 32) + (size_t)hwbase * 32;
        const int cp = t & 31, hw0 = t >> 5;
        #pragma unroll
        for (int i = 0; i < 4; ++i) {
            const int hw = hw0 + i * 8;
            dst[hw * 32 + cp] =
                __floats2half2_rn(tile[2 * cp][hw], tile[2 * cp + 1][hw]);
        }
    } else if (blk < 544) {
        // E[b][nv][n][j*4+k2] = sum_k1 coefx[nv,j,k1,n] *
        //   (wz0*coefy[nv,k1,k2,m0c] + wz1*coefy[nv,k1,k2,m1c])
        const int p  = (blk - 512) * 256 + t;        // 8192 half2 pairs
        const int b  = p >> 11, nv = (p >> 7) & 15, n = (p >> 3) & 15, q = p & 7;
        const float th  = theta[b] * 0.31830988618379067154f;
        const float zf  = (th + 1.0f) * 8.0f - 0.5f;
        const float zfl = floorf(zf);
        const float fz  = zf - zfl;
        const int   m0  = (int)zfl;
        const float wz0 = (m0 >= 0 && m0 <= 15) ? (1.0f - fz) : 0.0f;
        const float wz1 = (m0 + 1 >= 0 && m0 + 1 <= 15) ? fz : 0.0f;
        const int   m0c = min(max(m0, 0), 15), m1c = min(max(m0 + 1, 0), 15);
        float ev[2];
        #pragma unroll
        for (int s = 0; s < 2; ++s) {
            const int idx = 2 * q + s, j = idx >> 2, k2 = idx & 3;
            float e = 0.0f;
            #pragma unroll
            for (int k1 = 0; k1 < 4; ++k1) {
                const float a  = coefx[nv * 256 + (j * 4 + k1) * 16 + n];
                const float bm = wz0 * coefy[nv * 256 + (k1 * 4 + k2) * 16 + m0c]
                               + wz1 * coefy[nv * 256 + (k1 * 4 + k2) * 16 + m1c];
                e += a * bm;
            }
            ev[s] = e;
        }
        ((__half2*)(ws + EWS_OFF))[p] = __floats2half2_rn(ev[0], ev[1]);
    } else {
        // C repack: Cws[nv][o][k2*4+l] = coefr[nv,k2,l,o]
        const int p = (blk - 544) * 256 + t;
        if (p < 2048) {
            const int nv = p >> 7, o = (p >> 3) & 15, q = p & 7;
            const float c0 = coefr[nv * 256 + (2 * q + 0) * 16 + o];
            const float c1 = coefr[nv * 256 + (2 * q + 1) * 16 + o];
            ((__half2*)(ws + CWS_OFF))[p] = __floats2half2_rn(c0, c1);
        }
    }
}

// LDS C/E layout: 16B units, unit(nv,o,u) = o*49 + nv*3 + u (u=0,1 data).
__global__ __launch_bounds__(256) void seprot_kernel(
    const float* __restrict__ grid1,
    const float* __restrict__ grid2,
    const char*  __restrict__ ws,
    float* __restrict__ out)
{
    __shared__ H2x4 sC[16 * 49];        // 12.25 KiB
    __shared__ H2x4 sE[16 * 49];        // 12.25 KiB
    __shared__ float sOut[16][17][4];   // 4.25 KiB store-coalescing stage

    const int t   = threadIdx.x;
    const int blk = blockIdx.x;
    const int b      = blk >> 8;             // block-uniform
    const int hwbase = (blk & 255) << 4;     // 16 pixels per block
    const int pg = t >> 4;                   // pixel in block (0..15)
    const int nv = t & 15;                   // lane-group = 16 nv of one pixel
    const int hw = hwbase + pg;

    // ---- stage C + E[b] (coalesced copy, padding applied here) ----
    {
        const H2x4* Cw = (const H2x4*)(ws + CWS_OFF);
        const H2x4* Ew = (const H2x4*)(ws + EWS_OFF) + b * 512;
        #pragma unroll
        for (int k = 0; k < 2; ++k) {
            const int i   = t + k * 256;
            const int wnv = i >> 5, wo = (i >> 1) & 15, wu = i & 1;
            const int du  = wo * 49 + wnv * 3 + wu;
            sC[du] = Cw[i];
            sE[du] = Ew[i];
        }
    }
    __syncthreads();

    // ---- per-pixel warp geometry (redundant across the 16 nv lanes) ----
    const float2 g2  = ((const float2*)grid2)[b * HWN + hw];
    const float  sxf = rintf((g2.x + 1.0f) * (0.5f * IW) - 0.5f);
    const float  syf = rintf((g2.y + 1.0f) * (0.5f * IH) - 0.5f);
    const bool valid = (sxf >= 0.0f) && (sxf <= (float)(IW - 1)) &&
                       (syf >= 0.0f) && (syf <= (float)(IH - 1));

    float acc[4] = {0.0f, 0.0f, 0.0f, 0.0f};

    if (valid) {
        const int sx = (int)sxf, sy = (int)syf;
        const __half2 zero2 = __floats2half2_rn(0.0f, 0.0f);

        #pragma unroll
        for (int tap = 0; tap < 9; ++tap) {
            const int di = tap / 3 - 1, dj = tap % 3 - 1;
            const int ty = sy + di, tx = sx + dj;
            const bool inb = ((unsigned)ty < (unsigned)IH) && ((unsigned)tx < (unsigned)IW);
            const int pix = min(max(ty, 0), IH - 1) * IW + min(max(tx, 0), IW - 1);

            // lgn 4-vec f16: 16 nv-lanes read 16 consecutive 8B -> 128B segment
            H2x2 lgu = ((const H2x2*)ws)[(b * HWN + pix) * 16 + nv];
            __half2 lg01 = inb ? lgu.a : zero2;   // OOB unfold tap -> zero window
            __half2 lg23 = inb ? lgu.b : zero2;

            // d = g2(center) - g1(tap); g1 broadcasts within the 16-lane group
            const float2 g1 = ((const float2*)grid1)[b * HWN + pix];
            const float dxc = g2.x - g1.x;
            const float dyc = g2.y - g1.y;

            // x -> coefr o axis
            const float xf  = (dxc + 1.0f) * (0.5f * NSN) - 0.5f;
            const float xfl = floorf(xf);
            const float fx  = xf - xfl;
            const int   o0  = (int)xfl;
            const float wx0 = (o0 >= 0 && o0 <= NSN - 1) ? (1.0f - fx) : 0.0f;
            const float wx1 = (o0 + 1 >= 0 && o0 + 1 <= NSN - 1) ? fx : 0.0f;
            const int   o0c = min(max(o0, 0), NSN - 1);
            const int   o1c = min(max(o0 + 1, 0), NSN - 1);

            // y -> coefx n axis
            const float yf  = (dyc + 1.0f) * (0.5f * NSN) - 0.5f;
            const float yfl = floorf(yf);
            const float fy  = yf - yfl;
            const int   n0  = (int)yfl;
            const float wy0 = (n0 >= 0 && n0 <= NSN - 1) ? (1.0f - fy) : 0.0f;
            const float wy1 = (n0 + 1 >= 0 && n0 + 1 <= NSN - 1) ? fy : 0.0f;
            const int   n0c = min(max(n0, 0), NSN - 1);
            const int   n1c = min(max(n0 + 1, 0), NSN - 1);

            const __half2 wx0h = __floats2half2_rn(wx0, wx0);
            const __half2 wx1h = __floats2half2_rn(wx1, wx1);
            const __half2 wy0h = __floats2half2_rn(wy0, wy0);
            const __half2 wy1h = __floats2half2_rn(wy1, wy1);

            // blended C rows (packed f16): bl[q] over [k2*2 + lpair]
            const H2x4 c0a = sC[o0c * 49 + nv * 3 + 0];
            const H2x4 c0b = sC[o0c * 49 + nv * 3 + 1];
            const H2x4 c1a = sC[o1c * 49 + nv * 3 + 0];
            const H2x4 c1b = sC[o1c * 49 + nv * 3 + 1];
            __half2 bl[8];
            #pragma unroll
            for (int k = 0; k < 4; ++k) {
                bl[k]     = __hfma2(c0a.h[k], wx0h, __hmul2(c1a.h[k], wx1h));
                bl[4 + k] = __hfma2(c0b.h[k], wx0h, __hmul2(c1b.h[k], wx1h));
            }
            // v_k2 = C'(x) . lg   (reduce each half2 pair in f32)
            float vf[4];
            #pragma unroll
            for (int k2 = 0; k2 < 4; ++k2) {
                const __half2 sv = __hfma2(bl[2 * k2 + 1], lg23,
                                           __hmul2(bl[2 * k2], lg01));
                vf[k2] = __low2float(sv) + __high2float(sv);
            }
            const __half2 v01 = __floats2half2_rn(vf[0], vf[1]);
            const __half2 v23 = __floats2half2_rn(vf[2], vf[3]);

            // blended E rows, then acc_j += E'(y) . v  (f32 accumulate)
            const H2x4 e0a = sE[n0c * 49 + nv * 3 + 0];
            const H2x4 e0b = sE[n0c * 49 + nv * 3 + 1];
            const H2x4 e1a = sE[n1c * 49 + nv * 3 + 0];
            const H2x4 e1b = sE[n1c * 49 + nv * 3 + 1];
            __half2 eb[8];
            #pragma unroll
            for (int k = 0; k < 4; ++k) {
                eb[k]     = __hfma2(e0a.h[k], wy0h, __hmul2(e1a.h[k], wy1h));
                eb[4 + k] = __hfma2(e0b.h[k], wy0h, __hmul2(e1b.h[k], wy1h));
            }
            #pragma unroll
            for (int j = 0; j < 4; ++j) {
                const __half2 sa = __hfma2(eb[2 * j + 1], v23,
                                           __hmul2(eb[2 * j], v01));
                acc[j] += __low2float(sa) + __high2float(sa);
            }
        }
    }

    // ---- store-coalescing LDS round-trip: swap nv<->pg lane roles ----
    *(float4*)&sOut[pg][nv][0] = make_float4(acc[0], acc[1], acc[2], acc[3]);
    __syncthreads();
    {
        const int nv2 = t >> 4, pg2 = t & 15;
        #pragma unroll
        for (int j = 0; j < 4; ++j)
            out[(b * 64 + nv2 * 4 + j) * HWN + hwbase + pg2] = sOut[pg2][nv2][j];
    }
}

extern "C" void kernel_launch(void* const* d_in, const int* in_sizes, int n_in,
                              void* d_out, int out_size, void* d_ws, size_t ws_size,
                              hipStream_t stream) {
    const float* grid1 = (const float*)d_in[0];
    const float* grid2 = (const float*)d_in[1];
    const float* theta = (const float*)d_in[2];
    const float* lgn   = (const float*)d_in[3];
    const float* coefx = (const float*)d_in[4];
    const float* coefy = (const float*)d_in[5];
    const float* coefr = (const float*)d_in[6];
    float*       outp  = (float*)d_out;
    char*        ws    = (char*)d_ws;

    // prep: blocks 0..511 transpose lgn->f16; 512..543 E; 544..551 C repack
    hipLaunchKernelGGL(prep_kernel, dim3(552), dim3(256), 0, stream,
                       lgn, theta, coefx, coefy, coefr, ws);

    // main: 1024 blocks, 16 pixels x 16 nv per block
    hipLaunchKernelGGL(seprot_kernel, dim3(BB * 256), dim3(256), 0, stream,
                       grid1, grid2, ws, outp);
}